// Round 4
// baseline (484.840 us; speedup 1.0000x reference)
//
#include <hip/hip_runtime.h>
#include <math.h>
#include <stdint.h>

#define L_  1024
#define B_  2
#define D_  1024
#define H_  16
#define DH_ 64
#define M_  1024
#define T_  2048
#define SCALE_ 0.125f

typedef unsigned short ushort;
typedef short bf16x8 __attribute__((ext_vector_type(8)));
typedef float f32x4 __attribute__((ext_vector_type(4)));
typedef unsigned short u16x4v __attribute__((ext_vector_type(4)));
typedef unsigned short u16x8v __attribute__((ext_vector_type(8)));

#define MFMA16(a,b,c) __builtin_amdgcn_mfma_f32_16x16x32_bf16(a,b,c,0,0,0)

static __device__ __forceinline__ ushort f2bf(float x) {
    uint32_t u = __float_as_uint(x);
    uint32_t r = (u + 0x7FFFu + ((u >> 16) & 1u)) >> 16;
    return (ushort)r;
}
static __device__ __forceinline__ float bf2f(ushort h) {
    return __uint_as_float(((uint32_t)h) << 16);
}

// ---------------------------------------------------------------------------
// fp32 -> bf16 convert
// ---------------------------------------------------------------------------
__global__ __launch_bounds__(256) void cvt_bf16(const float* __restrict__ src,
                                                ushort* __restrict__ dst, int n) {
    int i = (blockIdx.x * 256 + threadIdx.x) * 8;
    if (i >= n) return;
    float4 a = *(const float4*)(src + i);
    float4 b = *(const float4*)(src + i + 4);
    u16x8v o;
    o[0] = f2bf(a.x); o[1] = f2bf(a.y); o[2] = f2bf(a.z); o[3] = f2bf(a.w);
    o[4] = f2bf(b.x); o[5] = f2bf(b.y); o[6] = f2bf(b.z); o[7] = f2bf(b.w);
    *(u16x8v*)(dst + i) = o;
}

// ---------------------------------------------------------------------------
// fp32 [K][N] -> bf16 [N][K] transpose+convert. 32x32 tiles, 256 thr.
// ---------------------------------------------------------------------------
__global__ __launch_bounds__(256) void trans_cvt(const float* __restrict__ src,
                                                 ushort* __restrict__ dst,
                                                 int K, int N) {
    __shared__ float t[32][33];
    int k0 = blockIdx.x * 32, n0 = blockIdx.y * 32;
    int tid = threadIdx.x;
    int r = tid >> 3, c4 = (tid & 7) * 4;
    float4 v = *(const float4*)(src + (size_t)(k0 + r) * N + n0 + c4);
    t[r][c4 + 0] = v.x; t[r][c4 + 1] = v.y; t[r][c4 + 2] = v.z; t[r][c4 + 3] = v.w;
    __syncthreads();
    u16x4v o;
    o[0] = f2bf(t[c4 + 0][r]); o[1] = f2bf(t[c4 + 1][r]);
    o[2] = f2bf(t[c4 + 2][r]); o[3] = f2bf(t[c4 + 3][r]);
    *(u16x4v*)(dst + (size_t)(n0 + r) * K + k0 + c4) = o;
}

// ---------------------------------------------------------------------------
// bf16 MFMA GEMM: C[64x64] = A[M][1024] @ Wt[N][1024]^T
// omode 0: q -> qu=(+bu), qv=(+bv), layout [bh][L][64]
// omode 1: kv -> n<1024: k row-major [bh][T][64]; else v TRANSPOSED [bh][64][T]
// omode 2: r -> [bh][T][64]
// omode 3: outF[m][n] = acc + resid  (fp32)
// ---------------------------------------------------------------------------
__global__ __launch_bounds__(256) void gemm_bf16(
    const ushort* __restrict__ A, const ushort* __restrict__ Wt,
    int omode,
    const float* __restrict__ bu, const float* __restrict__ bv,
    ushort* __restrict__ outA, ushort* __restrict__ outB,
    const float* __restrict__ resid, float* __restrict__ outF)
{
    __shared__ ushort Al[64][40];
    __shared__ ushort Bl[64][40];
    int tid = threadIdx.x;
    int M0 = blockIdx.x * 64, N0 = blockIdx.y * 64;
    int wid = tid >> 6, lane = tid & 63, quad = lane >> 4, jl = lane & 15;
    int m0w = (wid >> 1) * 32, n0w = (wid & 1) * 32;
    int sr = tid >> 2, sc = (tid & 3) * 8;

    f32x4 acc[2][2];
    #pragma unroll
    for (int i = 0; i < 2; ++i)
        #pragma unroll
        for (int j = 0; j < 2; ++j) acc[i][j] = (f32x4){0.f, 0.f, 0.f, 0.f};

    for (int k0 = 0; k0 < 1024; k0 += 32) {
        *(u16x8v*)&Al[sr][sc] = *(const u16x8v*)(A  + (size_t)(M0 + sr) * 1024 + k0 + sc);
        *(u16x8v*)&Bl[sr][sc] = *(const u16x8v*)(Wt + (size_t)(N0 + sr) * 1024 + k0 + sc);
        __syncthreads();
        bf16x8 a0 = *(const bf16x8*)&Al[m0w + jl][quad * 8];
        bf16x8 a1 = *(const bf16x8*)&Al[m0w + 16 + jl][quad * 8];
        bf16x8 b0 = *(const bf16x8*)&Bl[n0w + jl][quad * 8];
        bf16x8 b1 = *(const bf16x8*)&Bl[n0w + 16 + jl][quad * 8];
        acc[0][0] = MFMA16(a0, b0, acc[0][0]);
        acc[0][1] = MFMA16(a0, b1, acc[0][1]);
        acc[1][0] = MFMA16(a1, b0, acc[1][0]);
        acc[1][1] = MFMA16(a1, b1, acc[1][1]);
        __syncthreads();
    }

    #pragma unroll
    for (int ms = 0; ms < 2; ++ms)
        #pragma unroll
        for (int ns = 0; ns < 2; ++ns)
            #pragma unroll
            for (int r = 0; r < 4; ++r) {
                int gm = M0 + m0w + 16 * ms + quad * 4 + r;
                int gn = N0 + n0w + 16 * ns + jl;
                float v = acc[ms][ns][r];
                if (omode == 0) {
                    int l = gm >> 1, b = gm & 1;
                    int h = gn >> 6, d = gn & 63;
                    size_t o = ((size_t)((b << 4) | h) * 1024 + l) * 64 + d;
                    outA[o] = f2bf(v + bu[gn]);
                    outB[o] = f2bf(v + bv[gn]);
                } else if (omode == 1) {
                    int t = gm >> 1, b = gm & 1;
                    int nn = gn & 1023;
                    int h = nn >> 6, d = nn & 63;
                    if (gn < 1024)
                        outA[((size_t)((b << 4) | h) * 2048 + t) * 64 + d] = f2bf(v);
                    else
                        outB[((size_t)((b << 4) | h) * 64 + d) * 2048 + t] = f2bf(v);
                } else if (omode == 2) {
                    int t = gm >> 1, b = gm & 1;
                    int h = gn >> 6, d = gn & 63;
                    outA[((size_t)((b << 4) | h) * 2048 + t) * 64 + d] = f2bf(v);
                } else {
                    outF[(size_t)gm * 1024 + gn] = v + resid[(size_t)gm * 1024 + gn];
                }
            }
}

// ---------------------------------------------------------------------------
// Barrier-free single-pass attention, 64-key chunks, j-split x4.
// Block = 4 independent waves (16 q-rows each) x one bh x one j-segment.
// No-max softmax: p = exp(s), l = sum p; partials combined additively.
// ---------------------------------------------------------------------------
__global__ __launch_bounds__(256, 4) void attn_fused3(
    const ushort* __restrict__ qu, const ushort* __restrict__ qv,
    const ushort* __restrict__ kb, const ushort* __restrict__ Vt,
    const ushort* __restrict__ rb,
    float* __restrict__ Opart, float* __restrict__ lpart,
    ushort* __restrict__ AMw)
{
    __shared__ ushort Pl[4][2][16][76];   // stride 38 dwords: b128 reads 2-way free

    int tid = threadIdx.x, wid = tid >> 6, lane = tid & 63;
    int quad = lane >> 4, jl = lane & 15;
    int I0 = blockIdx.x * 64;
    int bh = blockIdx.y;
    int seg = blockIdx.z;
    int i0w = I0 + wid * 16;
    int irow = i0w + quad * 4;

    const ushort* kp  = kb + (size_t)bh * 2048 * 64;
    const ushort* vtp = Vt + (size_t)bh * 64 * 2048;
    const ushort* rp  = rb + (size_t)bh * 2048 * 64;
    const ushort* qup = qu + (size_t)bh * 1024 * 64;
    const ushort* qvp = qv + (size_t)bh * 1024 * 64;

    bf16x8 quA[2], qvA[2];
    quA[0] = *(const bf16x8*)(qup + (size_t)(i0w + jl) * 64 + quad * 8);
    quA[1] = *(const bf16x8*)(qup + (size_t)(i0w + jl) * 64 + 32 + quad * 8);
    qvA[0] = *(const bf16x8*)(qvp + (size_t)(i0w + jl) * 64 + quad * 8);
    qvA[1] = *(const bf16x8*)(qvp + (size_t)(i0w + jl) * 64 + 32 + quad * 8);

    // 64-key chunks; covers j < 64*nc (<= 2048), wave-uniform
    int nc = (i0w + 1039) / 64 + 1;
    int cb_ = (nc * seg) >> 2;
    int ce_ = (nc * (seg + 1)) >> 2;

    f32x4 z = (f32x4){0.f, 0.f, 0.f, 0.f};
    f32x4 oacc[4];
    #pragma unroll
    for (int nt = 0; nt < 4; ++nt) oacc[nt] = z;
    float lsum[4] = {0.f, 0.f, 0.f, 0.f};

    for (int c = cb_; c < ce_; ++c) {
        int j0 = c * 64;
        int par = c & 1;
        // ---- AC: 4 column-subtiles of 16 ----
        f32x4 ac[4];
        #pragma unroll
        for (int su = 0; su < 4; ++su) {
            const ushort* krow = kp + (size_t)(j0 + su * 16 + jl) * 64;
            bf16x8 k0 = *(const bf16x8*)(krow + quad * 8);
            bf16x8 k1 = *(const bf16x8*)(krow + 32 + quad * 8);
            f32x4 t = MFMA16(quA[0], k0, z);
            ac[su] = MFMA16(quA[1], k1, t);
        }
        // ---- BD windows: 5 n-tiles covering r-rows d0 .. d0+79 ----
        int d0 = 1008 + j0 - i0w;
        f32x4 bt[5];
        #pragma unroll
        for (int nt = 0; nt < 5; ++nt) {
            int rr = d0 + nt * 16 + jl;
            rr = min(max(rr, 0), 2047);
            const ushort* rrow = rp + (size_t)rr * 64;
            bf16x8 r0 = *(const bf16x8*)(rrow + quad * 8);
            bf16x8 r1 = *(const bf16x8*)(rrow + 32 + quad * 8);
            f32x4 t = MFMA16(qvA[0], r0, z);
            bt[nt] = MFMA16(qvA[1], r1, t);
        }
        // ---- diagonal extraction, exp, stage P ----
        #pragma unroll
        for (int r = 0; r < 4; ++r) {
            int ii = quad * 4 + r;
            int src = (quad << 4) | ((jl + 15 - ii) & 15);
            float bs[5];
            #pragma unroll
            for (int nt = 0; nt < 5; ++nt) bs[nt] = __shfl(bt[nt][r], src);
            bool hi = (jl > ii);      // nt = su + (jl > ii), same for all su
            #pragma unroll
            for (int su = 0; su < 4; ++su) {
                float bd = hi ? bs[su + 1] : bs[su];
                float sv = (ac[su][r] + bd) * SCALE_;
                int j = j0 + su * 16 + jl;
                float p = (j <= irow + r + M_) ? __expf(fminf(sv, 60.f)) : 0.f;
                lsum[r] += p;
                Pl[wid][par][ii][su * 16 + jl] = f2bf(p);
            }
        }
        asm volatile("s_waitcnt lgkmcnt(0)" ::: "memory");
        bf16x8 pA0 = *(const bf16x8*)&Pl[wid][par][jl][quad * 8];
        bf16x8 pA1 = *(const bf16x8*)&Pl[wid][par][jl][32 + quad * 8];
        // ---- plane write: 16 rows x 64 cols, 32 B/lane ----
        {
            int prow = lane >> 2, pcol = (lane & 3) * 16;
            u16x8v pv0 = *(const u16x8v*)&Pl[wid][par][prow][pcol];
            u16x8v pv1 = *(const u16x8v*)&Pl[wid][par][prow][pcol + 8];
            ushort* dst = AMw + (size_t)bh * 2097152 +
                          (size_t)(i0w + prow) * 2048 + j0 + pcol;
            *(u16x8v*)dst = pv0;
            *(u16x8v*)(dst + 8) = pv1;
        }
        // ---- PV: k = 64 keys -> 2 MFMAs per 16-col d-tile ----
        #pragma unroll
        for (int nt = 0; nt < 4; ++nt) {
            const ushort* vrow = vtp + (size_t)(nt * 16 + jl) * 2048 + j0;
            bf16x8 vB0 = *(const bf16x8*)(vrow + quad * 8);
            bf16x8 vB1 = *(const bf16x8*)(vrow + 32 + quad * 8);
            oacc[nt] = MFMA16(pA0, vB0, oacc[nt]);
            oacc[nt] = MFMA16(pA1, vB1, oacc[nt]);
        }
    }

    // ---- epilogue: combine partials ----
    #pragma unroll
    for (int r = 0; r < 4; ++r) {
        #pragma unroll
        for (int off = 1; off < 16; off <<= 1) lsum[r] += __shfl_xor(lsum[r], off);
        if (jl == 0) atomicAdd(&lpart[(size_t)bh * 1024 + irow + r], lsum[r]);
    }
    #pragma unroll
    for (int nt = 0; nt < 4; ++nt)
        #pragma unroll
        for (int r = 0; r < 4; ++r)
            atomicAdd(&Opart[((size_t)bh * 1024 + irow + r) * 64 + nt * 16 + jl],
                      oacc[nt][r]);
}

// ---------------------------------------------------------------------------
// Combine O partials: O = Opart / l -> bf16 row-major [L*B][1024];
// also emit linvs[bh][i] = (1/l)/32 for am_reduce.
// ---------------------------------------------------------------------------
__global__ __launch_bounds__(256) void o_combine(
    const float* __restrict__ Opart, const float* __restrict__ lpart,
    ushort* __restrict__ OvecB, float* __restrict__ linvs)
{
    int idx8 = (blockIdx.x * 256 + threadIdx.x) * 8;   // over 2M floats
    int bh = idx8 >> 16;
    int rem = idx8 & 65535;
    int i = rem >> 6, d0 = rem & 63;
    float linv = 1.f / lpart[(size_t)bh * 1024 + i];
    float4 a = *(const float4*)(Opart + idx8);
    float4 b4 = *(const float4*)(Opart + idx8 + 4);
    u16x8v o;
    o[0] = f2bf(a.x * linv);  o[1] = f2bf(a.y * linv);
    o[2] = f2bf(a.z * linv);  o[3] = f2bf(a.w * linv);
    o[4] = f2bf(b4.x * linv); o[5] = f2bf(b4.y * linv);
    o[6] = f2bf(b4.z * linv); o[7] = f2bf(b4.w * linv);
    int b = bh >> 4, h = bh & 15;
    *(u16x8v*)(OvecB + (size_t)(i * 2 + b) * 1024 + h * 64 + d0) = o;
    if (d0 == 0) linvs[(size_t)bh * 1024 + i] = linv * 0.03125f;
}

// ---------------------------------------------------------------------------
// AM[i][j] = sum_bh plane[bh][i][j] * linvs[bh][i], re-masked.
// grid 2048 x 256 thr x 4 elems.
// ---------------------------------------------------------------------------
__global__ __launch_bounds__(256) void am_reduce(const ushort* __restrict__ AMw,
                                                 const float* __restrict__ linvs,
                                                 float* __restrict__ AM) {
    size_t idx = ((size_t)blockIdx.x * 256 + threadIdx.x) * 4;
    int i = (int)(idx >> 11);
    int j0 = (int)(idx & 2047);
    float a0 = 0.f, a1 = 0.f, a2 = 0.f, a3 = 0.f;
    for (int p = 0; p < 32; ++p) {
        float lv = linvs[(size_t)p * 1024 + i];
        u16x4v v = *(const u16x4v*)(AMw + (size_t)p * 2097152 + idx);
        a0 += bf2f(v[0]) * lv;
        a1 += bf2f(v[1]) * lv;
        a2 += bf2f(v[2]) * lv;
        a3 += bf2f(v[3]) * lv;
    }
    int jmax = i + M_;
    float4 o;
    o.x = (j0 + 0 <= jmax) ? a0 : 0.f;
    o.y = (j0 + 1 <= jmax) ? a1 : 0.f;
    o.z = (j0 + 2 <= jmax) ? a2 : 0.f;
    o.w = (j0 + 3 <= jmax) ? a3 : 0.f;
    *(float4*)(AM + idx) = o;
}

// ---------------------------------------------------------------------------
// LayerNorm over D=1024, one block per row
// ---------------------------------------------------------------------------
__global__ __launch_bounds__(256) void ln_kernel(
    const float* __restrict__ hbuf,
    const float* __restrict__ gamma, const float* __restrict__ beta,
    float* __restrict__ out)
{
    __shared__ float rs[4], rss[4];
    int row = blockIdx.x;
    int tid = threadIdx.x;
    const float* hp = hbuf + (size_t)row * 1024;
    float4 h4 = *(const float4*)(hp + (tid << 2));
    float s = h4.x + h4.y + h4.z + h4.w;
    float ss = h4.x * h4.x + h4.y * h4.y + h4.z * h4.z + h4.w * h4.w;
    #pragma unroll
    for (int o = 32; o > 0; o >>= 1) {
        s  += __shfl_down(s, o);
        ss += __shfl_down(ss, o);
    }
    if ((tid & 63) == 0) { rs[tid >> 6] = s; rss[tid >> 6] = ss; }
    __syncthreads();
    float tot  = rs[0] + rs[1] + rs[2] + rs[3];
    float tots = rss[0] + rss[1] + rss[2] + rss[3];
    float mu = tot * (1.f / 1024.f);
    float var = tots * (1.f / 1024.f) - mu * mu;
    float rstd = rsqrtf(var + 1e-5f);
    float4 g4 = *(const float4*)(gamma + (tid << 2));
    float4 b4 = *(const float4*)(beta + (tid << 2));
    float4 o4;
    o4.x = (h4.x - mu) * rstd * g4.x + b4.x;
    o4.y = (h4.y - mu) * rstd * g4.y + b4.y;
    o4.z = (h4.z - mu) * rstd * g4.z + b4.z;
    o4.w = (h4.w - mu) * rstd * g4.w + b4.w;
    *(float4*)(out + (size_t)row * 1024 + (tid << 2)) = o4;
}

extern "C" void kernel_launch(void* const* d_in, const int* in_sizes, int n_in,
                              void* d_out, int out_size, void* d_ws, size_t ws_size,
                              hipStream_t stream) {
    const float* x       = (const float*)d_in[0];
    const float* pos_emb = (const float*)d_in[1];
    const float* memory  = (const float*)d_in[2];
    const float* bu      = (const float*)d_in[3];
    const float* bv      = (const float*)d_in[4];
    const float* Wq      = (const float*)d_in[6];
    const float* Wkv     = (const float*)d_in[7];
    const float* Wrel    = (const float*)d_in[8];
    const float* Wo      = (const float*)d_in[9];
    const float* gamma   = (const float*)d_in[10];
    const float* beta    = (const float*)d_in[11];

    float* out = (float*)d_out;
    float* AM  = out + (size_t)2097152;       // attn_matrix [L][T]

    ushort* cb    = (ushort*)d_ws;            // [4096][1024]
    ushort* pb    = cb    + 4194304;          // [4096][1024]
    ushort* Wqt   = pb    + 4194304;          // [1024][1024]
    ushort* Wkvt  = Wqt   + 1048576;          // [2048][1024]
    ushort* Wrelt = Wkvt  + 2097152;          // [1024][1024]
    ushort* Wot   = Wrelt + 1048576;          // [1024][1024]
    ushort* quB   = Wot   + 1048576;          // [32][1024][64]
    ushort* qvB   = quB   + 2097152;
    ushort* kbB   = qvB   + 2097152;          // [32][2048][64]
    ushort* VtB   = kbB   + 4194304;          // [32][64][2048]
    ushort* rbB   = VtB   + 4194304;          // [32][2048][64]
    ushort* OvecB = rbB   + 4194304;          // [2048][1024]
    float*  hbuf  = (float*)(OvecB + 2097152);// [2048][1024] fp32
    float*  Opart = hbuf  + 2097152;          // [32][1024][64] fp32
    float*  lpart = Opart + 2097152;          // [32][1024] fp32
    float*  linvs = lpart + 32768;            // [32][1024] fp32
    ushort* AMw   = (ushort*)(linvs + 32768); // [32][1024][2048] bf16 (128 MB)

    dim3 blk(256);
    // converts
    cvt_bf16<<<1024, blk, 0, stream>>>(memory, cb, 2097152);
    cvt_bf16<<<1024, blk, 0, stream>>>(x, cb + 2097152, 2097152);
    cvt_bf16<<<2048, blk, 0, stream>>>(pos_emb, pb, 4194304);
    trans_cvt<<<dim3(32, 32), blk, 0, stream>>>(Wq,   Wqt,   1024, 1024);
    trans_cvt<<<dim3(32, 64), blk, 0, stream>>>(Wkv,  Wkvt,  1024, 2048);
    trans_cvt<<<dim3(32, 32), blk, 0, stream>>>(Wrel, Wrelt, 1024, 1024);
    trans_cvt<<<dim3(32, 32), blk, 0, stream>>>(Wo,   Wot,   1024, 1024);
    hipMemsetAsync(Opart, 0, (size_t)2097152 * sizeof(float), stream);
    hipMemsetAsync(lpart, 0, (size_t)32768 * sizeof(float), stream);

    // projections
    gemm_bf16<<<dim3(32, 16), blk, 0, stream>>>(cb + 2097152, Wqt, 0, bu, bv,
                                                quB, qvB, nullptr, nullptr);
    gemm_bf16<<<dim3(64, 32), blk, 0, stream>>>(cb, Wkvt, 1, nullptr, nullptr,
                                                kbB, VtB, nullptr, nullptr);
    gemm_bf16<<<dim3(64, 16), blk, 0, stream>>>(pb, Wrelt, 2, nullptr, nullptr,
                                                rbB, nullptr, nullptr, nullptr);
    // attention (barrier-free, 64-key chunks, j-split x4)
    attn_fused3<<<dim3(16, 32, 4), blk, 0, stream>>>(quB, qvB, kbB, VtB, rbB,
                                                     Opart, lpart, AMw);
    // combine partials -> OvecB + linvs
    o_combine<<<1024, blk, 0, stream>>>(Opart, lpart, OvecB, linvs);
    // output projection + residual
    gemm_bf16<<<dim3(32, 16), blk, 0, stream>>>(OvecB, Wot, 3, nullptr, nullptr,
                                                nullptr, nullptr, x, hbuf);
    // layernorm
    ln_kernel<<<2048, blk, 0, stream>>>(hbuf, gamma, beta, out);
    // attn_matrix reduction
    am_reduce<<<2048, blk, 0, stream>>>(AMw, linvs, AM);
}

// Round 5
// 448.977 us; speedup vs baseline: 1.0799x; 1.0799x over previous
//
#include <hip/hip_runtime.h>
#include <math.h>
#include <stdint.h>

#define L_  1024
#define B_  2
#define D_  1024
#define H_  16
#define DH_ 64
#define M_  1024
#define T_  2048
#define SCALE_ 0.125f

typedef unsigned short ushort;
typedef short bf16x8 __attribute__((ext_vector_type(8)));
typedef float f32x4 __attribute__((ext_vector_type(4)));
typedef unsigned short u16x4v __attribute__((ext_vector_type(4)));
typedef unsigned short u16x8v __attribute__((ext_vector_type(8)));

#define MFMA16(a,b,c) __builtin_amdgcn_mfma_f32_16x16x32_bf16(a,b,c,0,0,0)

static __device__ __forceinline__ ushort f2bf(float x) {
    uint32_t u = __float_as_uint(x);
    uint32_t r = (u + 0x7FFFu + ((u >> 16) & 1u)) >> 16;
    return (ushort)r;
}
static __device__ __forceinline__ float bf2f(ushort h) {
    return __uint_as_float(((uint32_t)h) << 16);
}

// ---------------------------------------------------------------------------
// fp32 -> bf16 convert
// ---------------------------------------------------------------------------
__global__ __launch_bounds__(256) void cvt_bf16(const float* __restrict__ src,
                                                ushort* __restrict__ dst, int n) {
    int i = (blockIdx.x * 256 + threadIdx.x) * 8;
    if (i >= n) return;
    float4 a = *(const float4*)(src + i);
    float4 b = *(const float4*)(src + i + 4);
    u16x8v o;
    o[0] = f2bf(a.x); o[1] = f2bf(a.y); o[2] = f2bf(a.z); o[3] = f2bf(a.w);
    o[4] = f2bf(b.x); o[5] = f2bf(b.y); o[6] = f2bf(b.z); o[7] = f2bf(b.w);
    *(u16x8v*)(dst + i) = o;
}

// ---------------------------------------------------------------------------
// fp32 [K][N] -> bf16 [N][K] transpose+convert. 32x32 tiles, 256 thr.
// ---------------------------------------------------------------------------
__global__ __launch_bounds__(256) void trans_cvt(const float* __restrict__ src,
                                                 ushort* __restrict__ dst,
                                                 int K, int N) {
    __shared__ float t[32][33];
    int k0 = blockIdx.x * 32, n0 = blockIdx.y * 32;
    int tid = threadIdx.x;
    int r = tid >> 3, c4 = (tid & 7) * 4;
    float4 v = *(const float4*)(src + (size_t)(k0 + r) * N + n0 + c4);
    t[r][c4 + 0] = v.x; t[r][c4 + 1] = v.y; t[r][c4 + 2] = v.z; t[r][c4 + 3] = v.w;
    __syncthreads();
    u16x4v o;
    o[0] = f2bf(t[c4 + 0][r]); o[1] = f2bf(t[c4 + 1][r]);
    o[2] = f2bf(t[c4 + 2][r]); o[3] = f2bf(t[c4 + 3][r]);
    *(u16x4v*)(dst + (size_t)(n0 + r) * K + k0 + c4) = o;
}

// ---------------------------------------------------------------------------
// bf16 MFMA GEMM: C[64x64] = A[M][1024] @ Wt[N][1024]^T
// omode 0: q -> qu=(+bu), qv=(+bv), layout [bh][L][64]
// omode 1: kv -> n<1024: k row-major [bh][T][64]; else v TRANSPOSED [bh][64][T]
// omode 2: r -> [bh][T][64]
// omode 3: outF[m][n] = acc + resid  (fp32)
// ---------------------------------------------------------------------------
__global__ __launch_bounds__(256) void gemm_bf16(
    const ushort* __restrict__ A, const ushort* __restrict__ Wt,
    int omode,
    const float* __restrict__ bu, const float* __restrict__ bv,
    ushort* __restrict__ outA, ushort* __restrict__ outB,
    const float* __restrict__ resid, float* __restrict__ outF)
{
    __shared__ ushort Al[64][40];
    __shared__ ushort Bl[64][40];
    int tid = threadIdx.x;
    int M0 = blockIdx.x * 64, N0 = blockIdx.y * 64;
    int wid = tid >> 6, lane = tid & 63, quad = lane >> 4, jl = lane & 15;
    int m0w = (wid >> 1) * 32, n0w = (wid & 1) * 32;
    int sr = tid >> 2, sc = (tid & 3) * 8;

    f32x4 acc[2][2];
    #pragma unroll
    for (int i = 0; i < 2; ++i)
        #pragma unroll
        for (int j = 0; j < 2; ++j) acc[i][j] = (f32x4){0.f, 0.f, 0.f, 0.f};

    for (int k0 = 0; k0 < 1024; k0 += 32) {
        *(u16x8v*)&Al[sr][sc] = *(const u16x8v*)(A  + (size_t)(M0 + sr) * 1024 + k0 + sc);
        *(u16x8v*)&Bl[sr][sc] = *(const u16x8v*)(Wt + (size_t)(N0 + sr) * 1024 + k0 + sc);
        __syncthreads();
        bf16x8 a0 = *(const bf16x8*)&Al[m0w + jl][quad * 8];
        bf16x8 a1 = *(const bf16x8*)&Al[m0w + 16 + jl][quad * 8];
        bf16x8 b0 = *(const bf16x8*)&Bl[n0w + jl][quad * 8];
        bf16x8 b1 = *(const bf16x8*)&Bl[n0w + 16 + jl][quad * 8];
        acc[0][0] = MFMA16(a0, b0, acc[0][0]);
        acc[0][1] = MFMA16(a0, b1, acc[0][1]);
        acc[1][0] = MFMA16(a1, b0, acc[1][0]);
        acc[1][1] = MFMA16(a1, b1, acc[1][1]);
        __syncthreads();
    }

    #pragma unroll
    for (int ms = 0; ms < 2; ++ms)
        #pragma unroll
        for (int ns = 0; ns < 2; ++ns)
            #pragma unroll
            for (int r = 0; r < 4; ++r) {
                int gm = M0 + m0w + 16 * ms + quad * 4 + r;
                int gn = N0 + n0w + 16 * ns + jl;
                float v = acc[ms][ns][r];
                if (omode == 0) {
                    int l = gm >> 1, b = gm & 1;
                    int h = gn >> 6, d = gn & 63;
                    size_t o = ((size_t)((b << 4) | h) * 1024 + l) * 64 + d;
                    outA[o] = f2bf(v + bu[gn]);
                    outB[o] = f2bf(v + bv[gn]);
                } else if (omode == 1) {
                    int t = gm >> 1, b = gm & 1;
                    int nn = gn & 1023;
                    int h = nn >> 6, d = nn & 63;
                    if (gn < 1024)
                        outA[((size_t)((b << 4) | h) * 2048 + t) * 64 + d] = f2bf(v);
                    else
                        outB[((size_t)((b << 4) | h) * 64 + d) * 2048 + t] = f2bf(v);
                } else if (omode == 2) {
                    int t = gm >> 1, b = gm & 1;
                    int h = gn >> 6, d = gn & 63;
                    outA[((size_t)((b << 4) | h) * 2048 + t) * 64 + d] = f2bf(v);
                } else {
                    outF[(size_t)gm * 1024 + gn] = v + resid[(size_t)gm * 1024 + gn];
                }
            }
}

// ---------------------------------------------------------------------------
// Barrier-free single-pass attention, 64-key chunks, XCD-swizzled grid.
// lin = blockIdx.x (0..2047): xcd = lin&7 owns bh in [xcd*4, xcd*4+4) so the
// per-XCD L2 working set (K/V/R/Q for 4 heads ~= 4 MB) fits in 4 MB L2.
// No-max softmax: p = exp(s), l = sum p; partials combined additively.
// ---------------------------------------------------------------------------
__global__ __launch_bounds__(256) void attn_fused4(
    const ushort* __restrict__ qu, const ushort* __restrict__ qv,
    const ushort* __restrict__ kb, const ushort* __restrict__ Vt,
    const ushort* __restrict__ rb,
    float* __restrict__ Opart, float* __restrict__ lpart,
    ushort* __restrict__ AMw)
{
    __shared__ ushort Pl[4][2][16][76];   // stride 38 dwords: b128 reads 2-way free

    int tid = threadIdx.x, wid = tid >> 6, lane = tid & 63;
    int quad = lane >> 4, jl = lane & 15;

    // XCD-aware decode (round-robin dispatch assumption; perf-only heuristic)
    int lin  = blockIdx.x;
    int xcd  = lin & 7;
    int slot = lin >> 3;
    int bh   = (xcd << 2) | (slot & 3);
    int r2   = slot >> 2;
    int I0   = (r2 & 15) * 64;
    int seg  = r2 >> 4;

    int i0w = I0 + wid * 16;
    int irow = i0w + quad * 4;

    const ushort* kp  = kb + (size_t)bh * 2048 * 64;
    const ushort* vtp = Vt + (size_t)bh * 64 * 2048;
    const ushort* rp  = rb + (size_t)bh * 2048 * 64;
    const ushort* qup = qu + (size_t)bh * 1024 * 64;
    const ushort* qvp = qv + (size_t)bh * 1024 * 64;

    bf16x8 quA[2], qvA[2];
    quA[0] = *(const bf16x8*)(qup + (size_t)(i0w + jl) * 64 + quad * 8);
    quA[1] = *(const bf16x8*)(qup + (size_t)(i0w + jl) * 64 + 32 + quad * 8);
    qvA[0] = *(const bf16x8*)(qvp + (size_t)(i0w + jl) * 64 + quad * 8);
    qvA[1] = *(const bf16x8*)(qvp + (size_t)(i0w + jl) * 64 + 32 + quad * 8);

    // 64-key chunks; covers j < 64*nc (<= 2048), wave-uniform
    int nc = (i0w + 1039) / 64 + 1;
    int cb_ = (nc * seg) >> 2;
    int ce_ = (nc * (seg + 1)) >> 2;

    f32x4 z = (f32x4){0.f, 0.f, 0.f, 0.f};
    f32x4 oacc[4];
    #pragma unroll
    for (int nt = 0; nt < 4; ++nt) oacc[nt] = z;
    float lsum[4] = {0.f, 0.f, 0.f, 0.f};

    for (int c = cb_; c < ce_; ++c) {
        int j0 = c * 64;
        int par = c & 1;
        // ---- AC: 4 column-subtiles of 16 ----
        f32x4 ac[4];
        #pragma unroll
        for (int su = 0; su < 4; ++su) {
            const ushort* krow = kp + (size_t)(j0 + su * 16 + jl) * 64;
            bf16x8 k0 = *(const bf16x8*)(krow + quad * 8);
            bf16x8 k1 = *(const bf16x8*)(krow + 32 + quad * 8);
            f32x4 t = MFMA16(quA[0], k0, z);
            ac[su] = MFMA16(quA[1], k1, t);
        }
        // ---- BD windows: 5 n-tiles covering r-rows d0 .. d0+79 ----
        int d0 = 1008 + j0 - i0w;
        f32x4 bt[5];
        #pragma unroll
        for (int nt = 0; nt < 5; ++nt) {
            int rr = d0 + nt * 16 + jl;
            rr = min(max(rr, 0), 2047);
            const ushort* rrow = rp + (size_t)rr * 64;
            bf16x8 r0 = *(const bf16x8*)(rrow + quad * 8);
            bf16x8 r1 = *(const bf16x8*)(rrow + 32 + quad * 8);
            f32x4 t = MFMA16(qvA[0], r0, z);
            bt[nt] = MFMA16(qvA[1], r1, t);
        }
        // ---- diagonal extraction, exp, stage P ----
        #pragma unroll
        for (int r = 0; r < 4; ++r) {
            int ii = quad * 4 + r;
            int src = (quad << 4) | ((jl + 15 - ii) & 15);
            float bs[5];
            #pragma unroll
            for (int nt = 0; nt < 5; ++nt) bs[nt] = __shfl(bt[nt][r], src);
            bool hi = (jl > ii);      // nt = su + (jl > ii), same for all su
            #pragma unroll
            for (int su = 0; su < 4; ++su) {
                float bd = hi ? bs[su + 1] : bs[su];
                float sv = (ac[su][r] + bd) * SCALE_;
                int j = j0 + su * 16 + jl;
                float p = (j <= irow + r + M_) ? __expf(fminf(sv, 60.f)) : 0.f;
                lsum[r] += p;
                Pl[wid][par][ii][su * 16 + jl] = f2bf(p);
            }
        }
        asm volatile("s_waitcnt lgkmcnt(0)" ::: "memory");
        bf16x8 pA0 = *(const bf16x8*)&Pl[wid][par][jl][quad * 8];
        bf16x8 pA1 = *(const bf16x8*)&Pl[wid][par][jl][32 + quad * 8];
        // ---- plane write: 16 rows x 64 cols, 32 B/lane, non-temporal ----
        {
            int prow = lane >> 2, pcol = (lane & 3) * 16;
            u16x8v pv0 = *(const u16x8v*)&Pl[wid][par][prow][pcol];
            u16x8v pv1 = *(const u16x8v*)&Pl[wid][par][prow][pcol + 8];
            ushort* dst = AMw + (size_t)bh * 2097152 +
                          (size_t)(i0w + prow) * 2048 + j0 + pcol;
            __builtin_nontemporal_store(pv0, (u16x8v*)dst);
            __builtin_nontemporal_store(pv1, (u16x8v*)(dst + 8));
        }
        // ---- PV: k = 64 keys -> 2 MFMAs per 16-col d-tile ----
        #pragma unroll
        for (int nt = 0; nt < 4; ++nt) {
            const ushort* vrow = vtp + (size_t)(nt * 16 + jl) * 2048 + j0;
            bf16x8 vB0 = *(const bf16x8*)(vrow + quad * 8);
            bf16x8 vB1 = *(const bf16x8*)(vrow + 32 + quad * 8);
            oacc[nt] = MFMA16(pA0, vB0, oacc[nt]);
            oacc[nt] = MFMA16(pA1, vB1, oacc[nt]);
        }
    }

    // ---- epilogue: combine partials ----
    #pragma unroll
    for (int r = 0; r < 4; ++r) {
        #pragma unroll
        for (int off = 1; off < 16; off <<= 1) lsum[r] += __shfl_xor(lsum[r], off);
        if (jl == 0) atomicAdd(&lpart[(size_t)bh * 1024 + irow + r], lsum[r]);
    }
    #pragma unroll
    for (int nt = 0; nt < 4; ++nt)
        #pragma unroll
        for (int r = 0; r < 4; ++r)
            atomicAdd(&Opart[((size_t)bh * 1024 + irow + r) * 64 + nt * 16 + jl],
                      oacc[nt][r]);
}

// ---------------------------------------------------------------------------
// Combine O partials: O = Opart / l -> bf16 row-major [L*B][1024];
// also emit linvs[bh][i] = (1/l)/32 for am_reduce.
// ---------------------------------------------------------------------------
__global__ __launch_bounds__(256) void o_combine(
    const float* __restrict__ Opart, const float* __restrict__ lpart,
    ushort* __restrict__ OvecB, float* __restrict__ linvs)
{
    int idx8 = (blockIdx.x * 256 + threadIdx.x) * 8;   // over 2M floats
    int bh = idx8 >> 16;
    int rem = idx8 & 65535;
    int i = rem >> 6, d0 = rem & 63;
    float linv = 1.f / lpart[(size_t)bh * 1024 + i];
    float4 a = *(const float4*)(Opart + idx8);
    float4 b4 = *(const float4*)(Opart + idx8 + 4);
    u16x8v o;
    o[0] = f2bf(a.x * linv);  o[1] = f2bf(a.y * linv);
    o[2] = f2bf(a.z * linv);  o[3] = f2bf(a.w * linv);
    o[4] = f2bf(b4.x * linv); o[5] = f2bf(b4.y * linv);
    o[6] = f2bf(b4.z * linv); o[7] = f2bf(b4.w * linv);
    int b = bh >> 4, h = bh & 15;
    *(u16x8v*)(OvecB + (size_t)(i * 2 + b) * 1024 + h * 64 + d0) = o;
    if (d0 == 0) linvs[(size_t)bh * 1024 + i] = linv * 0.03125f;
}

// ---------------------------------------------------------------------------
// AM[i][j] = sum_bh plane[bh][i][j] * linvs[bh][i], re-masked.
// Skips reading the masked region entirely. grid 2048 x 256 thr x 4 elems.
// ---------------------------------------------------------------------------
__global__ __launch_bounds__(256) void am_reduce(const ushort* __restrict__ AMw,
                                                 const float* __restrict__ linvs,
                                                 float* __restrict__ AM) {
    size_t idx = ((size_t)blockIdx.x * 256 + threadIdx.x) * 4;
    int i = (int)(idx >> 11);
    int j0 = (int)(idx & 2047);
    int jmax = i + M_;
    if (j0 > jmax) {
        *(float4*)(AM + idx) = (float4){0.f, 0.f, 0.f, 0.f};
        return;
    }
    float a0 = 0.f, a1 = 0.f, a2 = 0.f, a3 = 0.f;
    for (int p = 0; p < 32; ++p) {
        float lv = linvs[(size_t)p * 1024 + i];
        u16x4v v = __builtin_nontemporal_load(
            (const u16x4v*)(AMw + (size_t)p * 2097152 + idx));
        a0 += bf2f(v[0]) * lv;
        a1 += bf2f(v[1]) * lv;
        a2 += bf2f(v[2]) * lv;
        a3 += bf2f(v[3]) * lv;
    }
    float4 o;
    o.x = a0;
    o.y = (j0 + 1 <= jmax) ? a1 : 0.f;
    o.z = (j0 + 2 <= jmax) ? a2 : 0.f;
    o.w = (j0 + 3 <= jmax) ? a3 : 0.f;
    *(float4*)(AM + idx) = o;
}

// ---------------------------------------------------------------------------
// LayerNorm over D=1024, one block per row
// ---------------------------------------------------------------------------
__global__ __launch_bounds__(256) void ln_kernel(
    const float* __restrict__ hbuf,
    const float* __restrict__ gamma, const float* __restrict__ beta,
    float* __restrict__ out)
{
    __shared__ float rs[4], rss[4];
    int row = blockIdx.x;
    int tid = threadIdx.x;
    const float* hp = hbuf + (size_t)row * 1024;
    float4 h4 = *(const float4*)(hp + (tid << 2));
    float s = h4.x + h4.y + h4.z + h4.w;
    float ss = h4.x * h4.x + h4.y * h4.y + h4.z * h4.z + h4.w * h4.w;
    #pragma unroll
    for (int o = 32; o > 0; o >>= 1) {
        s  += __shfl_down(s, o);
        ss += __shfl_down(ss, o);
    }
    if ((tid & 63) == 0) { rs[tid >> 6] = s; rss[tid >> 6] = ss; }
    __syncthreads();
    float tot  = rs[0] + rs[1] + rs[2] + rs[3];
    float tots = rss[0] + rss[1] + rss[2] + rss[3];
    float mu = tot * (1.f / 1024.f);
    float var = tots * (1.f / 1024.f) - mu * mu;
    float rstd = rsqrtf(var + 1e-5f);
    float4 g4 = *(const float4*)(gamma + (tid << 2));
    float4 b4 = *(const float4*)(beta + (tid << 2));
    float4 o4;
    o4.x = (h4.x - mu) * rstd * g4.x + b4.x;
    o4.y = (h4.y - mu) * rstd * g4.y + b4.y;
    o4.z = (h4.z - mu) * rstd * g4.z + b4.z;
    o4.w = (h4.w - mu) * rstd * g4.w + b4.w;
    *(float4*)(out + (size_t)row * 1024 + (tid << 2)) = o4;
}

extern "C" void kernel_launch(void* const* d_in, const int* in_sizes, int n_in,
                              void* d_out, int out_size, void* d_ws, size_t ws_size,
                              hipStream_t stream) {
    const float* x       = (const float*)d_in[0];
    const float* pos_emb = (const float*)d_in[1];
    const float* memory  = (const float*)d_in[2];
    const float* bu      = (const float*)d_in[3];
    const float* bv      = (const float*)d_in[4];
    const float* Wq      = (const float*)d_in[6];
    const float* Wkv     = (const float*)d_in[7];
    const float* Wrel    = (const float*)d_in[8];
    const float* Wo      = (const float*)d_in[9];
    const float* gamma   = (const float*)d_in[10];
    const float* beta    = (const float*)d_in[11];

    float* out = (float*)d_out;
    float* AM  = out + (size_t)2097152;       // attn_matrix [L][T]

    ushort* cb    = (ushort*)d_ws;            // [4096][1024]
    ushort* pb    = cb    + 4194304;          // [4096][1024]
    ushort* Wqt   = pb    + 4194304;          // [1024][1024]
    ushort* Wkvt  = Wqt   + 1048576;          // [2048][1024]
    ushort* Wrelt = Wkvt  + 2097152;          // [1024][1024]
    ushort* Wot   = Wrelt + 1048576;          // [1024][1024]
    ushort* quB   = Wot   + 1048576;          // [32][1024][64]
    ushort* qvB   = quB   + 2097152;
    ushort* kbB   = qvB   + 2097152;          // [32][2048][64]
    ushort* VtB   = kbB   + 4194304;          // [32][64][2048]
    ushort* rbB   = VtB   + 4194304;          // [32][2048][64]
    ushort* OvecB = rbB   + 4194304;          // [2048][1024]
    float*  hbuf  = (float*)(OvecB + 2097152);// [2048][1024] fp32
    float*  Opart = hbuf  + 2097152;          // [32][1024][64] fp32
    float*  lpart = Opart + 2097152;          // [32][1024] fp32
    float*  linvs = lpart + 32768;            // [32][1024] fp32
    ushort* AMw   = (ushort*)(linvs + 32768); // [32][1024][2048] bf16 (128 MB)

    dim3 blk(256);
    // converts
    cvt_bf16<<<1024, blk, 0, stream>>>(memory, cb, 2097152);
    cvt_bf16<<<1024, blk, 0, stream>>>(x, cb + 2097152, 2097152);
    cvt_bf16<<<2048, blk, 0, stream>>>(pos_emb, pb, 4194304);
    trans_cvt<<<dim3(32, 32), blk, 0, stream>>>(Wq,   Wqt,   1024, 1024);
    trans_cvt<<<dim3(32, 64), blk, 0, stream>>>(Wkv,  Wkvt,  1024, 2048);
    trans_cvt<<<dim3(32, 32), blk, 0, stream>>>(Wrel, Wrelt, 1024, 1024);
    trans_cvt<<<dim3(32, 32), blk, 0, stream>>>(Wo,   Wot,   1024, 1024);
    hipMemsetAsync(Opart, 0, (size_t)2097152 * sizeof(float), stream);
    hipMemsetAsync(lpart, 0, (size_t)32768 * sizeof(float), stream);

    // projections
    gemm_bf16<<<dim3(32, 16), blk, 0, stream>>>(cb + 2097152, Wqt, 0, bu, bv,
                                                quB, qvB, nullptr, nullptr);
    gemm_bf16<<<dim3(64, 32), blk, 0, stream>>>(cb, Wkvt, 1, nullptr, nullptr,
                                                kbB, VtB, nullptr, nullptr);
    gemm_bf16<<<dim3(64, 16), blk, 0, stream>>>(pb, Wrelt, 2, nullptr, nullptr,
                                                rbB, nullptr, nullptr, nullptr);
    // attention (barrier-free, 64-key chunks, XCD-swizzled 1-D grid)
    attn_fused4<<<dim3(2048), blk, 0, stream>>>(quB, qvB, kbB, VtB, rbB,
                                                Opart, lpart, AMw);
    // combine partials -> OvecB + linvs
    o_combine<<<1024, blk, 0, stream>>>(Opart, lpart, OvecB, linvs);
    // output projection + residual
    gemm_bf16<<<dim3(32, 16), blk, 0, stream>>>(OvecB, Wot, 3, nullptr, nullptr,
                                                nullptr, nullptr, x, hbuf);
    // layernorm
    ln_kernel<<<2048, blk, 0, stream>>>(hbuf, gamma, beta, out);
    // attn_matrix reduction
    am_reduce<<<2048, blk, 0, stream>>>(AMw, linvs, AM);
}